// Round 9
// baseline (162.295 us; speedup 1.0000x reference)
//
#include <hip/hip_runtime.h>
#include <hip/hip_bf16.h>
#include <math.h>

// ===========================================================================
// DIAGNOSTIC ROUND: identical to r8's fused kernel, but the whole body
// (build -> MLP -> tail) runs REPS=4 times (idempotent; same outputs).
// Purpose: lift fused_kernel above the 40us harness fills in the top-5 so
// its counters become visible, and decompose fixed-vs-repeatable cost via
// body ~= (T4 - T1)/3. Next round reverts REPS to 1.
// ===========================================================================
#define REPS 4

typedef _Float16 f16x8 __attribute__((ext_vector_type(8)));
typedef _Float16 f16x4 __attribute__((ext_vector_type(4)));
typedef float    f32x4 __attribute__((ext_vector_type(4)));
typedef float    f32x2 __attribute__((ext_vector_type(2)));

__device__ __forceinline__ float ldin(const void* p, int i, int f32f) {
  return f32f ? ((const float*)p)[i]
              : __bfloat162float(((const __hip_bfloat16*)p)[i]);
}

__device__ __forceinline__ f32x4 MFMA(f16x8 a, f16x8 b, f32x4 c) {
  return __builtin_amdgcn_mfma_f32_16x16x32_f16(a, b, c, 0, 0, 0);
}

__device__ __forceinline__ float tanh_fast(float x) {
  float e = __expf(2.f * x);
  return 1.f - 2.f * __builtin_amdgcn_rcpf(e + 1.f);
}

__device__ __forceinline__ float redq(float v) {
  v += __shfl_xor(v, 16, 64);
  v += __shfl_xor(v, 32, 64);
  return v;
}

// ---- LDS panel layout (f16 units), fragment-linear ----
#define OFF_VW2   0
#define OFF_VW2T  4096
#define OFF_HW2   8192
#define OFF_HW2T  12288
#define OFF_HW3   16384
#define OFF_HW3T  20480
#define OFF_W1V   24576
#define OFF_W1H   26624
#define W_N       28672
// f32 constants
#define C_WGV0 0
#define C_WGV1 64
#define C_WGH0 128
#define C_WGH1 192
#define C_VB1  256
#define C_VB2  320
#define C_HB1  384
#define C_HB2  448
#define C_HB3  512
#define C_W4   576
#define C_K    640
#define C_HB4  656
#define C_N    658

__global__ __launch_bounds__(512, 1) void fused_kernel(
    const void* px, const void* pVW1, const void* pVb1, const void* pVW2, const void* pVb2,
    const void* pHW1, const void* pHb1, const void* pHW2, const void* pHb2,
    const void* pHW3, const void* pHb3, const void* pHW4, const void* pHb4,
    const void* pG0, const void* pK, float* out)
{
  __shared__ __align__(16) _Float16 sW[W_N];
  __shared__ __align__(16) _Float16 sAct[16][1024];
  __shared__ __align__(16) float sQPs[10][128];
  __shared__ __align__(16) float sC[C_N];
  __shared__ int sCnt;

  const int tid = threadIdx.x, lane = tid & 63, w = tid >> 6;
  const int n = lane & 15, q = lane >> 4;
  const int e0 = blockIdx.x * 128 + w * 16;

  // ---- dtype detection (once) ----
  if (tid == 0) sCnt = 0;
  __syncthreads();
  {
    const unsigned short* xbp = (const unsigned short*)px;
    int good = 0;
#pragma unroll
    for (int i = 0; i < 2; ++i) {
      int ex = (xbp[tid * 2 + i] >> 7) & 0xFF;
      good += (ex >= 97 && ex <= 157) ? 1 : 0;
    }
    atomicAdd(&sCnt, good);
  }
  __syncthreads();
  const int f32f = (sCnt >= 870) ? 0 : 1;

  // ---- x row (once; registers persist across reps) ----
  float xv[8];
  if (f32f) {
    const f32x4* xp = (const f32x4*)((const float*)px + (e0 + n) * 8);
    f32x4 x0 = xp[0], x1 = xp[1];
#pragma unroll
    for (int j = 0; j < 4; ++j) { xv[j] = x0[j]; xv[4 + j] = x1[j]; }
  } else {
    uint4 u = *(const uint4*)((const unsigned short*)px + (e0 + n) * 8);
    unsigned uu[4] = {u.x, u.y, u.z, u.w};
#pragma unroll
    for (int j = 0; j < 4; ++j) {
      xv[2 * j]     = __uint_as_float(uu[j] << 16);
      xv[2 * j + 1] = __uint_as_float(uu[j] & 0xffff0000u);
    }
  }

  auto ld8 = [&](const void* src, int i0, float* o) {
    if (f32f) {
      f32x4 a = *(const f32x4*)((const float*)src + i0);
      f32x4 b = *(const f32x4*)((const float*)src + i0 + 4);
#pragma unroll
      for (int j = 0; j < 4; ++j) { o[j] = a[j]; o[4 + j] = b[j]; }
    } else {
      uint4 u = *(const uint4*)((const unsigned short*)src + i0);
      unsigned uu[4] = {u.x, u.y, u.z, u.w};
#pragma unroll
      for (int j = 0; j < 4; ++j) {
        o[2 * j]     = __uint_as_float(uu[j] << 16);
        o[2 * j + 1] = __uint_as_float(uu[j] & 0xffff0000u);
      }
    }
  };

#pragma unroll 1
  for (int rep = 0; rep < REPS; ++rep) {

    // ---- gather-build panels into LDS ----
    {
      const int s8 = tid & 511;
      const int h  = ((s8 >> 7) << 4) | (s8 & 15);
      const int k0 = (((s8 >> 6) & 1) << 5) | (((s8 >> 4) & 3) << 3);
#pragma unroll
      for (int p = 0; p < 6; ++p) {
        const void* src = (p < 2) ? pVW2 : ((p < 4) ? pHW2 : pHW3);
        f16x8 v;
        if (p & 1) {
#pragma unroll
          for (int j = 0; j < 8; ++j)
            v[j] = (_Float16)ldin(src, (k0 + j) * 64 + h, f32f);
        } else {
          float o[8];
          ld8(src, h * 64 + k0, o);
#pragma unroll
          for (int j = 0; j < 8; ++j) v[j] = (_Float16)o[j];
        }
        *(f16x8*)(sW + p * 4096 + s8 * 8) = v;
      }
      {
        const int t2 = tid;
        const void* src = (t2 >> 8) ? pHW1 : pVW1;
        const int off = (t2 >> 8) ? OFF_W1H : OFF_W1V;
        const int ss = t2 & 255;
        const int mm = ss & 15, qq = (ss >> 4) & 3, ht = ss >> 6;
        float o[8];
        ld8(src, (ht * 16 + mm) * 8, o);
        f16x8 v;
#pragma unroll
        for (int j = 0; j < 8; ++j) {
          _Float16 hi = (_Float16)o[j];
          v[j] = (qq < 2) ? hi
               : ((qq == 2 && f32f) ? (_Float16)(o[j] - (float)hi) : (_Float16)0.f);
        }
        *(f16x8*)(sW + off + ss * 8) = v;
      }
    }

    // ---- constants into sC ----
    if (tid < 64) {
      float a0 = 0.f, a1 = 0.f, b0 = 0.f, b1 = 0.f;
#pragma unroll
      for (int nn = 0; nn < 8; ++nn) {
        float g0 = ldin(pG0, 2 * nn, f32f), g1 = ldin(pG0, 2 * nn + 1, f32f);
        float wv = ldin(pVW1, tid * 8 + nn, f32f), wh = ldin(pHW1, tid * 8 + nn, f32f);
        a0 += wv * g0; a1 += wv * g1; b0 += wh * g0; b1 += wh * g1;
      }
      sC[C_WGV0 + tid] = a0; sC[C_WGV1 + tid] = a1;
      sC[C_WGH0 + tid] = b0; sC[C_WGH1 + tid] = b1;
      sC[C_VB1 + tid] = ldin(pVb1, tid, f32f);
      sC[C_VB2 + tid] = ldin(pVb2, tid, f32f);
      sC[C_HB1 + tid] = ldin(pHb1, tid, f32f);
      sC[C_HB2 + tid] = ldin(pHb2, tid, f32f);
      sC[C_HB3 + tid] = ldin(pHb3, tid, f32f);
      sC[C_W4  + tid] = ldin(pHW4, tid, f32f);
    }
    if (tid < 16) sC[C_K + tid] = ldin(pK, tid, f32f);
    if (tid == 0) sC[C_HB4] = ldin(pHb4, 0, f32f);

    __syncthreads();   // barrier A: sW + sC ready

    float un0 = 0.f, un1 = 0.f;
    f16x8 xb;
#pragma unroll
    for (int j = 0; j < 8; ++j) {
      _Float16 hh = (_Float16)xv[j];
      float lo = xv[j] - (float)hh;
      xb[j] = (q == 1) ? (_Float16)lo : ((q == 3) ? (_Float16)0.f : hh);
      un0 -= xv[j] * sC[C_K + 2 * j];
      un1 -= xv[j] * sC[C_K + 2 * j + 1];
    }

    _Float16* bufV = sAct[2 * w];
    _Float16* bufH = sAct[2 * w + 1];

    auto gemm64x2 = [&](int poffV, int poffH, f32x4* accV, f32x4* accH) {
      f16x8 aV[8], aH[8];
#pragma unroll
      for (int i = 0; i < 8; ++i)
        aV[i] = *(const f16x8*)(sW + poffV + i * 512 + lane * 8);
#pragma unroll
      for (int i = 0; i < 8; ++i)
        aH[i] = *(const f16x8*)(sW + poffH + i * 512 + lane * 8);
      f16x8 bV0 = *(const f16x8*)(bufV + lane * 8);
      f16x8 bV1 = *(const f16x8*)(bufV + 512 + lane * 8);
      f16x8 bH0 = *(const f16x8*)(bufH + lane * 8);
      f16x8 bH1 = *(const f16x8*)(bufH + 512 + lane * 8);
#pragma unroll
      for (int ht = 0; ht < 4; ++ht) {
        f32x4 c = {0.f, 0.f, 0.f, 0.f};
        c = MFMA(aV[2 * ht], bV0, c);
        accV[ht] = MFMA(aV[2 * ht + 1], bV1, c);
        f32x4 d = {0.f, 0.f, 0.f, 0.f};
        d = MFMA(aH[2 * ht], bH0, d);
        accH[ht] = MFMA(aH[2 * ht + 1], bH1, d);
      }
    };
    auto gemm64 = [&](int poff, const _Float16* b, f32x4* acc) {
      f16x8 a[8];
#pragma unroll
      for (int i = 0; i < 8; ++i)
        a[i] = *(const f16x8*)(sW + poff + i * 512 + lane * 8);
      f16x8 b0 = *(const f16x8*)(b + lane * 8);
      f16x8 b1 = *(const f16x8*)(b + 512 + lane * 8);
#pragma unroll
      for (int ht = 0; ht < 4; ++ht) {
        f32x4 c = {0.f, 0.f, 0.f, 0.f};
        c = MFMA(a[2 * ht], b0, c);
        acc[ht] = MFMA(a[2 * ht + 1], b1, c);
      }
    };
    auto l1gemm2 = [&](f32x4* accV, f32x4* accH) {
      f16x8 aV[4], aH[4];
#pragma unroll
      for (int ht = 0; ht < 4; ++ht)
        aV[ht] = *(const f16x8*)(sW + OFF_W1V + ht * 512 + lane * 8);
#pragma unroll
      for (int ht = 0; ht < 4; ++ht)
        aH[ht] = *(const f16x8*)(sW + OFF_W1H + ht * 512 + lane * 8);
#pragma unroll
      for (int ht = 0; ht < 4; ++ht) {
        f32x4 c = {0.f, 0.f, 0.f, 0.f};
        accV[ht] = MFMA(aV[ht], xb, c);
        f32x4 d = {0.f, 0.f, 0.f, 0.f};
        accH[ht] = MFMA(aH[ht], xb, d);
      }
    };
    auto wst = [&](const f32x4* vals, _Float16* b) {
#pragma unroll
      for (int ht = 0; ht < 4; ++ht) {
        int aw = ((ht >> 1) << 9) + (((ht & 1) * 2 + (q >> 1)) << 7) + n * 8 + ((q & 1) << 2);
        f16x4 vh;
#pragma unroll
        for (int r = 0; r < 4; ++r) vh[r] = (_Float16)vals[ht][r];
        *(f16x4*)(b + aw) = vh;
      }
    };

    f32x4 accV[4], accH[4], tvV[4], tvH[4];
    f32x4 z1V[4], d1V[4], z1H[4], d1H[4], d2H[4];

    // ===== S1 =====
    l1gemm2(accV, accH);
#pragma unroll
    for (int ht = 0; ht < 4; ++ht) {
      int hb = ht * 16 + q * 4;
      f32x4 bV = *(const f32x4*)&sC[C_VB1 + hb];
      f32x4 bH = *(const f32x4*)&sC[C_HB1 + hb];
      z1V[ht] = accV[ht]; z1H[ht] = accH[ht];
#pragma unroll
      for (int r = 0; r < 4; ++r) {
        float t = tanh_fast(z1V[ht][r] + bV[r]);
        tvV[ht][r] = t; d1V[ht][r] = 1.f - t * t;
        t = tanh_fast(z1H[ht][r] + bH[r]);
        tvH[ht][r] = t; d1H[ht][r] = 1.f - t * t;
      }
    }
    wst(tvV, bufV); wst(tvH, bufH);

    // ===== S2 =====
    gemm64x2(OFF_VW2, OFF_HW2, accV, accH);
    float pV = 0.f;
#pragma unroll
    for (int ht = 0; ht < 4; ++ht) {
      int hb = ht * 16 + q * 4;
      f32x4 bV = *(const f32x4*)&sC[C_VB2 + hb];
      f32x4 bH = *(const f32x4*)&sC[C_HB2 + hb];
#pragma unroll
      for (int r = 0; r < 4; ++r) {
        float t = tanh_fast(accV[ht][r] + bV[r]);
        pV += t * t;
        tvV[ht][r] = t * (1.f - t * t);
        t = tanh_fast(accH[ht][r] + bH[r]);
        tvH[ht][r] = t; d2H[ht][r] = 1.f - t * t;
      }
    }
    wst(tvV, bufV); wst(tvH, bufH);

    // ===== S3 =====
    gemm64x2(OFF_VW2T, OFF_HW3, accV, accH);
    float pgvx = 0.f, plv0 = 0.f, plv1 = 0.f, pH = 0.f;
#pragma unroll
    for (int ht = 0; ht < 4; ++ht) {
      int hb = ht * 16 + q * 4;
      f32x4 g0 = *(const f32x4*)&sC[C_WGV0 + hb];
      f32x4 g1 = *(const f32x4*)&sC[C_WGV1 + hb];
      f32x4 bH = *(const f32x4*)&sC[C_HB3 + hb];
      f32x4 w4 = *(const f32x4*)&sC[C_W4 + hb];
#pragma unroll
      for (int r = 0; r < 4; ++r) {
        float wt = accV[ht][r] * d1V[ht][r];
        pgvx += wt * z1V[ht][r];
        plv0 += wt * g0[r]; plv1 += wt * g1[r];
        float t = tanh_fast(accH[ht][r] + bH[r]);
        pH += t * w4[r];
        tvH[ht][r] = w4[r] * (1.f - t * t);
      }
    }
    wst(tvH, bufH);

    // ===== S4 =====
    gemm64(OFF_HW3T, bufH, accH);
#pragma unroll
    for (int ht = 0; ht < 4; ++ht)
#pragma unroll
      for (int r = 0; r < 4; ++r) tvH[ht][r] = accH[ht][r] * d2H[ht][r];
    wst(tvH, bufH);

    // ===== S5 =====
    gemm64(OFF_HW2T, bufH, accH);
    float pghx = 0.f, plh0 = 0.f, plh1 = 0.f;
#pragma unroll
    for (int ht = 0; ht < 4; ++ht) {
      int hb = ht * 16 + q * 4;
      f32x4 g0 = *(const f32x4*)&sC[C_WGH0 + hb];
      f32x4 g1 = *(const f32x4*)&sC[C_WGH1 + hb];
#pragma unroll
      for (int r = 0; r < 4; ++r) {
        float wt = accH[ht][r] * d1H[ht][r];
        pghx += wt * z1H[ht][r];
        plh0 += wt * g0[r]; plh1 += wt * g1[r];
      }
    }

    {
      float a0 = redq(plh0), a1 = redq(plh1), a2 = redq(plv0), a3 = redq(plv1);
      float a4 = redq(pghx), a5 = redq(pgvx), a6 = redq(pV), a7 = redq(pH);
      if (q == 0) {
        int col = w * 16 + n;
        sQPs[0][col] = a0; sQPs[1][col] = a1; sQPs[2][col] = a2; sQPs[3][col] = a3;
        sQPs[4][col] = a4; sQPs[5][col] = a5; sQPs[6][col] = a6; sQPs[7][col] = a7;
        sQPs[8][col] = un0; sQPs[9][col] = un1;
      }
    }
    __syncthreads();   // barrier B: scalars ready

    if (w == 0 || w == 2) {
      // ====== QP tail: waves 0,2, full 64 lanes = 64 elems each ======
      const int col = (w >> 1) * 64 + lane;
      const int e = blockIdx.x * 128 + col;
      float gh0 = sQPs[0][col], gh1 = sQPs[1][col];
      float gv0 = sQPs[2][col], gv1 = sQPs[3][col];
      float ghx = sQPs[4][col], gvx = sQPs[5][col];
      float V   = 0.5f * sQPs[6][col];
      float H   = sQPs[7][col] + sC[C_HB4];
      float u0 = sQPs[8][col], u1 = sQPs[9][col];
      out[98304 + e]  = V;
      out[163840 + e] = H;

      const float im = 1.0f / 1.2f;
      const float sg = 1e-6f;
      const float d  = 2.f + sg;
      const float rd = 1.f / d;
      const float al = 1.f + im * im;
      const float be = al * (1.f - rd);
      float S00 = be * (gh0 * gh0 + gv0 * gv0) + d;
      float S11 = be * (gh1 * gh1 + gv1 * gv1) + d;
      float S01 = be * (gh0 * gh1 + gv0 * gv1);
      float idet = 1.f / (S00 * S11 - S01 * S01);

      f32x2 IM2; IM2[0] = 1.f; IM2[1] = im;
      f32x2 ghP; ghP[0] = gh0; ghP[1] = gh1;
      f32x2 gvP; gvP[0] = gv0; gvP[1] = gv1;
      f32x2 gHV0; gHV0[0] = gh0; gHV0[1] = gv0;
      f32x2 gHV1; gHV1[0] = gh1; gHV1[1] = gv1;
      f32x2 iA; iA[0] = S11 * idet;  iA[1] = -S01 * idet;
      f32x2 iB; iB[0] = -S01 * idet; iB[1] = S00 * idet;
      f32x2 nqP; nqP[0] = 2.f * u0; nqP[1] = 2.f * u1;
      f32x2 loA; loA[0] = ghx - H;      loA[1] = ghx * im - H;
      f32x2 hiB; hiB[0] = gvx - V;      hiB[1] = gvx * im - V;

      f32x2 ZA = {0.f, 0.f}, ZB = {0.f, 0.f}, ZC = {0.f, 0.f}, ZD = {0.f, 0.f};
      f32x2 YA = {0.f, 0.f}, YB = {0.f, 0.f}, YC = {0.f, 0.f}, YD = {0.f, 0.f};
      f32x2 X01 = {0.f, 0.f}, XP = {0.f, 0.f}, XS = {0.f, 0.f};

#pragma unroll 1
      for (int it = 0; it < 80; ++it) {
        f32x2 tA = ZA - YA, tB = ZB - YB, tC = ZC - YC, tD = ZD - YD;
        float tauh = tA[0] + im * tA[1];
        float tauv = tB[0] + im * tB[1];
        f32x2 bU = nqP + ghP * tauh + gvP * tauv;
        f32x2 bP = tC - tB - 100.f;
        f32x2 bS = tA + tD - 50.f;
        float pp = bP[0] + im * bP[1];
        float s2 = bS[0] + im * bS[1];
        f32x2 cb = ghP * s2 - gvP * pp;
        f32x2 ub = bU - cb * rd;
        X01 = iA * ub[0] + iB * ub[1];
        f32x2 gd = gHV0 * X01[0] + gHV1 * X01[1];
        XP = (bP + IM2 * gd[1]) * rd;
        XS = (bS - IM2 * gd[0]) * rd;
        f32x2 ztA = IM2 * gd[0] + XS;
        f32x2 ztB = IM2 * gd[1] - XP;

        f32x2 vv, zn;
        vv = ztA + YA; zn[0] = fmaxf(vv[0], loA[0]); zn[1] = fmaxf(vv[1], loA[1]);
        YA = vv - zn; ZA = zn;
        vv = ztB + YB; zn[0] = fminf(vv[0], hiB[0]); zn[1] = fminf(vv[1], hiB[1]);
        YB = vv - zn; ZB = zn;
        vv = XP + YC;  zn[0] = fmaxf(vv[0], 0.f);   zn[1] = fmaxf(vv[1], 0.f);
        YC = vv - zn; ZC = zn;
        vv = XS + YD;  zn[0] = fmaxf(vv[0], 0.f);   zn[1] = fmaxf(vv[1], 0.f);
        YD = vv - zn; ZD = zn;
      }

      float relax = 0.5f * (XP[0] + XP[1]);
      const float cc = 0.5f * (1.f + im);
      float Vdot = cc * (gv0 * X01[0] + gv1 * X01[1] - gvx);
      float Hdot = cc * (gh0 * X01[0] + gh1 * X01[1] - ghx);

      f32x2 uo; uo[0] = X01[0]; uo[1] = X01[1];
      *(f32x2*)&out[2 * e] = uo;
      out[65536 + e]  = relax;
      out[131072 + e] = Vdot;
      out[196608 + e] = Hdot;
    }

    __syncthreads();   // barrier C: rejoin before next rep's rebuild
  }
}

extern "C" void kernel_launch(void* const* d_in, const int* in_sizes, int n_in,
                              void* d_out, int out_size, void* d_ws, size_t ws_size,
                              hipStream_t stream) {
  (void)in_sizes; (void)n_in; (void)out_size; (void)d_ws; (void)ws_size;
  fused_kernel<<<256, 512, 0, stream>>>(
      d_in[0], d_in[1], d_in[2], d_in[3], d_in[4], d_in[5], d_in[6],
      d_in[7], d_in[8], d_in[9], d_in[10], d_in[11], d_in[12],
      d_in[13], d_in[14], (float*)d_out);
}

// Round 10
// 106.153 us; speedup vs baseline: 1.5289x; 1.5289x over previous
//
#include <hip/hip_runtime.h>
#include <hip/hip_bf16.h>
#include <math.h>

typedef _Float16 f16x8 __attribute__((ext_vector_type(8)));
typedef _Float16 f16x4 __attribute__((ext_vector_type(4)));
typedef float    f32x4 __attribute__((ext_vector_type(4)));
typedef float    f32x2 __attribute__((ext_vector_type(2)));

__device__ __forceinline__ float ldin(const void* p, int i, int f32f) {
  return f32f ? ((const float*)p)[i]
              : __bfloat162float(((const __hip_bfloat16*)p)[i]);
}

__device__ __forceinline__ f32x4 MFMA(f16x8 a, f16x8 b, f32x4 c) {
  return __builtin_amdgcn_mfma_f32_16x16x32_f16(a, b, c, 0, 0, 0);
}

__device__ __forceinline__ float tanh_fast(float x) {
  float e = __expf(2.f * x);
  return 1.f - 2.f * __builtin_amdgcn_rcpf(e + 1.f);
}

__device__ __forceinline__ float redq(float v) {
  v += __shfl_xor(v, 16, 64);
  v += __shfl_xor(v, 32, 64);
  return v;
}

// ---- LDS panel layout (f16 units), fragment-linear ----
#define OFF_VW2   0
#define OFF_VW2T  4096
#define OFF_HW2   8192
#define OFF_HW2T  12288
#define OFF_HW3   16384
#define OFF_HW3T  20480
#define OFF_W1V   24576
#define OFF_W1H   26624
#define W_N       28672
// f32 constants
#define C_WGV0 0
#define C_WGV1 64
#define C_WGH0 128
#define C_WGH1 192
#define C_VB1  256
#define C_VB2  320
#define C_HB1  384
#define C_HB2  448
#define C_HB3  512
#define C_W4   576
#define C_K    640
#define C_HB4  656
#define C_N    658

// ===========================================================================
// r10: occupancy restructure per r9 diagnostic (latency-bound, all pipes
// ~2/3 idle, 1 block/CU). Now 512 blocks x 256 thr, block owns 64 elems,
// 4 waves, wave owns 16 elems x all 64 h (MLP per-wave code unchanged).
// LDS ~77KB/block -> TWO independent blocks per CU: when one block stalls
// (build gathers, barriers, tail chain) the other issues. Tail = one full
// 64-lane wave per block (wave 0 or 2 by block parity to spread SIMDs).
// ===========================================================================
__global__ __launch_bounds__(256, 2) void fused_kernel(
    const void* px, const void* pVW1, const void* pVb1, const void* pVW2, const void* pVb2,
    const void* pHW1, const void* pHb1, const void* pHW2, const void* pHb2,
    const void* pHW3, const void* pHb3, const void* pHW4, const void* pHb4,
    const void* pG0, const void* pK, float* out)
{
  __shared__ __align__(16) _Float16 sW[W_N];          // 57.3 KB
  __shared__ __align__(16) _Float16 sAct[8][1024];    // 16 KB  [wave][V|H]
  __shared__ __align__(16) float sQPs[10][64];        // 2.5 KB
  __shared__ __align__(16) float sC[C_N];             // 2.6 KB
  __shared__ int sCnt;

  const int tid = threadIdx.x, lane = tid & 63, w = tid >> 6;
  const int n = lane & 15, q = lane >> 4;
  const int e0 = blockIdx.x * 64 + w * 16;

  // ---- dtype detection (512 samples) ----
  if (tid == 0) sCnt = 0;
  __syncthreads();
  {
    const unsigned short* xbp = (const unsigned short*)px;
    int good = 0;
#pragma unroll
    for (int i = 0; i < 2; ++i) {
      int ex = (xbp[tid * 2 + i] >> 7) & 0xFF;
      good += (ex >= 97 && ex <= 157) ? 1 : 0;
    }
    atomicAdd(&sCnt, good);
  }
  __syncthreads();
  const int f32f = (sCnt >= 435) ? 0 : 1;   // >=85% of 512 sane -> bf16 inputs

  // ---- x row (vector load), consumed after barrier ----
  float xv[8];
  if (f32f) {
    const f32x4* xp = (const f32x4*)((const float*)px + (e0 + n) * 8);
    f32x4 x0 = xp[0], x1 = xp[1];
#pragma unroll
    for (int j = 0; j < 4; ++j) { xv[j] = x0[j]; xv[4 + j] = x1[j]; }
  } else {
    uint4 u = *(const uint4*)((const unsigned short*)px + (e0 + n) * 8);
    unsigned uu[4] = {u.x, u.y, u.z, u.w};
#pragma unroll
    for (int j = 0; j < 4; ++j) {
      xv[2 * j]     = __uint_as_float(uu[j] << 16);
      xv[2 * j + 1] = __uint_as_float(uu[j] & 0xffff0000u);
    }
  }

  auto ld8 = [&](const void* src, int i0, float* o) {
    if (f32f) {
      f32x4 a = *(const f32x4*)((const float*)src + i0);
      f32x4 b = *(const f32x4*)((const float*)src + i0 + 4);
#pragma unroll
      for (int j = 0; j < 4; ++j) { o[j] = a[j]; o[4 + j] = b[j]; }
    } else {
      uint4 u = *(const uint4*)((const unsigned short*)src + i0);
      unsigned uu[4] = {u.x, u.y, u.z, u.w};
#pragma unroll
      for (int j = 0; j < 4; ++j) {
        o[2 * j]     = __uint_as_float(uu[j] << 16);
        o[2 * j + 1] = __uint_as_float(uu[j] & 0xffff0000u);
      }
    }
  };

  // ---- gather-build panels into LDS: 14 slots/thread (2 rounds of each) ----
  {
#pragma unroll
    for (int p = 0; p < 6; ++p) {
      const void* src = (p < 2) ? pVW2 : ((p < 4) ? pHW2 : pHW3);
#pragma unroll
      for (int half = 0; half < 2; ++half) {
        const int s8 = half * 256 + tid;
        const int h  = ((s8 >> 7) << 4) | (s8 & 15);
        const int k0 = (((s8 >> 6) & 1) << 5) | (((s8 >> 4) & 3) << 3);
        f16x8 v;
        if (p & 1) {
          // transposed panel: slot(h,k) holds M[k][h]
#pragma unroll
          for (int j = 0; j < 8; ++j)
            v[j] = (_Float16)ldin(src, (k0 + j) * 64 + h, f32f);
        } else {
          float o[8];
          ld8(src, h * 64 + k0, o);
#pragma unroll
          for (int j = 0; j < 8; ++j) v[j] = (_Float16)o[j];
        }
        *(f16x8*)(sW + p * 4096 + s8 * 8) = v;
      }
    }
    // packed layer-1 A-frags: 512 slots = 2 rounds
#pragma unroll
    for (int half = 0; half < 2; ++half) {
      const int t2 = half * 256 + tid;      // 0..511
      const void* src = (t2 >> 8) ? pHW1 : pVW1;
      const int off = (t2 >> 8) ? OFF_W1H : OFF_W1V;
      const int ss = t2 & 255;
      const int mm = ss & 15, qq = (ss >> 4) & 3, ht = ss >> 6;
      float o[8];
      ld8(src, (ht * 16 + mm) * 8, o);
      f16x8 v;
#pragma unroll
      for (int j = 0; j < 8; ++j) {
        _Float16 hi = (_Float16)o[j];
        v[j] = (qq < 2) ? hi
             : ((qq == 2 && f32f) ? (_Float16)(o[j] - (float)hi) : (_Float16)0.f);
      }
      *(f16x8*)(sW + off + ss * 8) = v;
    }
  }

  // ---- constants into sC ----
  if (tid < 64) {
    float a0 = 0.f, a1 = 0.f, b0 = 0.f, b1 = 0.f;
#pragma unroll
    for (int nn = 0; nn < 8; ++nn) {
      float g0 = ldin(pG0, 2 * nn, f32f), g1 = ldin(pG0, 2 * nn + 1, f32f);
      float wv = ldin(pVW1, tid * 8 + nn, f32f), wh = ldin(pHW1, tid * 8 + nn, f32f);
      a0 += wv * g0; a1 += wv * g1; b0 += wh * g0; b1 += wh * g1;
    }
    sC[C_WGV0 + tid] = a0; sC[C_WGV1 + tid] = a1;
    sC[C_WGH0 + tid] = b0; sC[C_WGH1 + tid] = b1;
    sC[C_VB1 + tid] = ldin(pVb1, tid, f32f);
    sC[C_VB2 + tid] = ldin(pVb2, tid, f32f);
    sC[C_HB1 + tid] = ldin(pHb1, tid, f32f);
    sC[C_HB2 + tid] = ldin(pHb2, tid, f32f);
    sC[C_HB3 + tid] = ldin(pHb3, tid, f32f);
    sC[C_W4  + tid] = ldin(pHW4, tid, f32f);
  }
  if (tid < 16) sC[C_K + tid] = ldin(pK, tid, f32f);
  if (tid == 0) sC[C_HB4] = ldin(pHb4, 0, f32f);

  __syncthreads();   // sW + sC ready

  float un0 = 0.f, un1 = 0.f;
  f16x8 xb;
#pragma unroll
  for (int j = 0; j < 8; ++j) {
    _Float16 hh = (_Float16)xv[j];
    float lo = xv[j] - (float)hh;
    xb[j] = (q == 1) ? (_Float16)lo : ((q == 3) ? (_Float16)0.f : hh);
    un0 -= xv[j] * sC[C_K + 2 * j];
    un1 -= xv[j] * sC[C_K + 2 * j + 1];
  }

  _Float16* bufV = sAct[2 * w];
  _Float16* bufH = sAct[2 * w + 1];

  auto gemm64x2 = [&](int poffV, int poffH, f32x4* accV, f32x4* accH) {
    f16x8 aV[8], aH[8];
#pragma unroll
    for (int i = 0; i < 8; ++i)
      aV[i] = *(const f16x8*)(sW + poffV + i * 512 + lane * 8);
#pragma unroll
    for (int i = 0; i < 8; ++i)
      aH[i] = *(const f16x8*)(sW + poffH + i * 512 + lane * 8);
    f16x8 bV0 = *(const f16x8*)(bufV + lane * 8);
    f16x8 bV1 = *(const f16x8*)(bufV + 512 + lane * 8);
    f16x8 bH0 = *(const f16x8*)(bufH + lane * 8);
    f16x8 bH1 = *(const f16x8*)(bufH + 512 + lane * 8);
#pragma unroll
    for (int ht = 0; ht < 4; ++ht) {
      f32x4 c = {0.f, 0.f, 0.f, 0.f};
      c = MFMA(aV[2 * ht], bV0, c);
      accV[ht] = MFMA(aV[2 * ht + 1], bV1, c);
      f32x4 d = {0.f, 0.f, 0.f, 0.f};
      d = MFMA(aH[2 * ht], bH0, d);
      accH[ht] = MFMA(aH[2 * ht + 1], bH1, d);
    }
  };
  auto gemm64 = [&](int poff, const _Float16* b, f32x4* acc) {
    f16x8 a[8];
#pragma unroll
    for (int i = 0; i < 8; ++i)
      a[i] = *(const f16x8*)(sW + poff + i * 512 + lane * 8);
    f16x8 b0 = *(const f16x8*)(b + lane * 8);
    f16x8 b1 = *(const f16x8*)(b + 512 + lane * 8);
#pragma unroll
    for (int ht = 0; ht < 4; ++ht) {
      f32x4 c = {0.f, 0.f, 0.f, 0.f};
      c = MFMA(a[2 * ht], b0, c);
      acc[ht] = MFMA(a[2 * ht + 1], b1, c);
    }
  };
  auto l1gemm2 = [&](f32x4* accV, f32x4* accH) {
    f16x8 aV[4], aH[4];
#pragma unroll
    for (int ht = 0; ht < 4; ++ht)
      aV[ht] = *(const f16x8*)(sW + OFF_W1V + ht * 512 + lane * 8);
#pragma unroll
    for (int ht = 0; ht < 4; ++ht)
      aH[ht] = *(const f16x8*)(sW + OFF_W1H + ht * 512 + lane * 8);
#pragma unroll
    for (int ht = 0; ht < 4; ++ht) {
      f32x4 c = {0.f, 0.f, 0.f, 0.f};
      accV[ht] = MFMA(aV[ht], xb, c);
      f32x4 d = {0.f, 0.f, 0.f, 0.f};
      accH[ht] = MFMA(aH[ht], xb, d);
    }
  };
  auto wst = [&](const f32x4* vals, _Float16* b) {
#pragma unroll
    for (int ht = 0; ht < 4; ++ht) {
      int aw = ((ht >> 1) << 9) + (((ht & 1) * 2 + (q >> 1)) << 7) + n * 8 + ((q & 1) << 2);
      f16x4 vh;
#pragma unroll
      for (int r = 0; r < 4; ++r) vh[r] = (_Float16)vals[ht][r];
      *(f16x4*)(b + aw) = vh;
    }
  };

  f32x4 accV[4], accH[4], tvV[4], tvH[4];
  f32x4 z1V[4], d1V[4], z1H[4], d1H[4], d2H[4];

  // ===== S1: layer-1 both nets =====
  l1gemm2(accV, accH);
#pragma unroll
  for (int ht = 0; ht < 4; ++ht) {
    int hb = ht * 16 + q * 4;
    f32x4 bV = *(const f32x4*)&sC[C_VB1 + hb];
    f32x4 bH = *(const f32x4*)&sC[C_HB1 + hb];
    z1V[ht] = accV[ht]; z1H[ht] = accH[ht];
#pragma unroll
    for (int r = 0; r < 4; ++r) {
      float t = tanh_fast(z1V[ht][r] + bV[r]);
      tvV[ht][r] = t; d1V[ht][r] = 1.f - t * t;
      t = tanh_fast(z1H[ht][r] + bH[r]);
      tvH[ht][r] = t; d1H[ht][r] = 1.f - t * t;
    }
  }
  wst(tvV, bufV); wst(tvH, bufH);

  // ===== S2: layer-2 both nets =====
  gemm64x2(OFF_VW2, OFF_HW2, accV, accH);
  float pV = 0.f;
#pragma unroll
  for (int ht = 0; ht < 4; ++ht) {
    int hb = ht * 16 + q * 4;
    f32x4 bV = *(const f32x4*)&sC[C_VB2 + hb];
    f32x4 bH = *(const f32x4*)&sC[C_HB2 + hb];
#pragma unroll
    for (int r = 0; r < 4; ++r) {
      float t = tanh_fast(accV[ht][r] + bV[r]);
      pV += t * t;
      tvV[ht][r] = t * (1.f - t * t);          // t2 * d2
      t = tanh_fast(accH[ht][r] + bH[r]);
      tvH[ht][r] = t; d2H[ht][r] = 1.f - t * t;
    }
  }
  wst(tvV, bufV); wst(tvH, bufH);

  // ===== S3: V bwd (W2^T) + H layer-3 (W3) =====
  gemm64x2(OFF_VW2T, OFF_HW3, accV, accH);
  float pgvx = 0.f, plv0 = 0.f, plv1 = 0.f, pH = 0.f;
#pragma unroll
  for (int ht = 0; ht < 4; ++ht) {
    int hb = ht * 16 + q * 4;
    f32x4 g0 = *(const f32x4*)&sC[C_WGV0 + hb];
    f32x4 g1 = *(const f32x4*)&sC[C_WGV1 + hb];
    f32x4 bH = *(const f32x4*)&sC[C_HB3 + hb];
    f32x4 w4 = *(const f32x4*)&sC[C_W4 + hb];
#pragma unroll
    for (int r = 0; r < 4; ++r) {
      float wt = accV[ht][r] * d1V[ht][r];
      pgvx += wt * z1V[ht][r];
      plv0 += wt * g0[r]; plv1 += wt * g1[r];
      float t = tanh_fast(accH[ht][r] + bH[r]);
      pH += t * w4[r];
      tvH[ht][r] = w4[r] * (1.f - t * t);      // v4
    }
  }
  wst(tvH, bufH);

  // ===== S4: H bwd (W3^T) =====
  gemm64(OFF_HW3T, bufH, accH);                // v3
#pragma unroll
  for (int ht = 0; ht < 4; ++ht)
#pragma unroll
    for (int r = 0; r < 4; ++r) tvH[ht][r] = accH[ht][r] * d2H[ht][r];   // bb
  wst(tvH, bufH);

  // ===== S5: H bwd (W2^T) =====
  gemm64(OFF_HW2T, bufH, accH);                // v2
  float pghx = 0.f, plh0 = 0.f, plh1 = 0.f;
#pragma unroll
  for (int ht = 0; ht < 4; ++ht) {
    int hb = ht * 16 + q * 4;
    f32x4 g0 = *(const f32x4*)&sC[C_WGH0 + hb];
    f32x4 g1 = *(const f32x4*)&sC[C_WGH1 + hb];
#pragma unroll
    for (int r = 0; r < 4; ++r) {
      float wt = accH[ht][r] * d1H[ht][r];
      pghx += wt * z1H[ht][r];
      plh0 += wt * g0[r]; plh1 += wt * g1[r];
    }
  }

  // ---- per-element scalars: reduce over q, hand off via LDS ----
  {
    float a0 = redq(plh0), a1 = redq(plh1), a2 = redq(plv0), a3 = redq(plv1);
    float a4 = redq(pghx), a5 = redq(pgvx), a6 = redq(pV), a7 = redq(pH);
    if (q == 0) {
      int col = w * 16 + n;
      sQPs[0][col] = a0; sQPs[1][col] = a1; sQPs[2][col] = a2; sQPs[3][col] = a3;
      sQPs[4][col] = a4; sQPs[5][col] = a5; sQPs[6][col] = a6; sQPs[7][col] = a7;
      sQPs[8][col] = un0; sQPs[9][col] = un1;
    }
  }
  __syncthreads();   // scalars ready

  // ====== QP tail: ONE full 64-lane wave per block (SIMD by block parity) ======
  const int tw = (blockIdx.x & 1) << 1;   // wave 0 or wave 2
  if (w != tw) return;

  const int col = lane;
  const int e = blockIdx.x * 64 + col;
  float gh0 = sQPs[0][col], gh1 = sQPs[1][col];
  float gv0 = sQPs[2][col], gv1 = sQPs[3][col];
  float ghx = sQPs[4][col], gvx = sQPs[5][col];
  float V   = 0.5f * sQPs[6][col];
  float H   = sQPs[7][col] + sC[C_HB4];
  un0 = sQPs[8][col]; un1 = sQPs[9][col];
  out[98304 + e]  = V;
  out[163840 + e] = H;

  const float im = 1.0f / 1.2f;
  const float sg = 1e-6f;
  const float d  = 2.f + sg;
  const float rd = 1.f / d;
  const float al = 1.f + im * im;
  const float be = al * (1.f - rd);
  float S00 = be * (gh0 * gh0 + gv0 * gv0) + d;
  float S11 = be * (gh1 * gh1 + gv1 * gv1) + d;
  float S01 = be * (gh0 * gh1 + gv0 * gv1);
  float idet = 1.f / (S00 * S11 - S01 * S01);

  // packed coefficient pairs
  f32x2 IM2; IM2[0] = 1.f; IM2[1] = im;
  f32x2 ghP; ghP[0] = gh0; ghP[1] = gh1;
  f32x2 gvP; gvP[0] = gv0; gvP[1] = gv1;
  f32x2 gHV0; gHV0[0] = gh0; gHV0[1] = gv0;
  f32x2 gHV1; gHV1[0] = gh1; gHV1[1] = gv1;
  f32x2 iA; iA[0] = S11 * idet;  iA[1] = -S01 * idet;
  f32x2 iB; iB[0] = -S01 * idet; iB[1] = S00 * idet;
  f32x2 nqP; nqP[0] = 2.f * un0; nqP[1] = 2.f * un1;
  f32x2 loA; loA[0] = ghx - H;      loA[1] = ghx * im - H;
  f32x2 hiB; hiB[0] = gvx - V;      hiB[1] = gvx * im - V;

  // state pairs: A=(Z0,Z2) B=(Z1,Z3) C=(Z4,Z5) D=(Z6,Z7)
  f32x2 ZA = {0.f, 0.f}, ZB = {0.f, 0.f}, ZC = {0.f, 0.f}, ZD = {0.f, 0.f};
  f32x2 YA = {0.f, 0.f}, YB = {0.f, 0.f}, YC = {0.f, 0.f}, YD = {0.f, 0.f};
  f32x2 X01 = {0.f, 0.f}, XP = {0.f, 0.f}, XS = {0.f, 0.f};

#pragma unroll 1
  for (int it = 0; it < 80; ++it) {
    f32x2 tA = ZA - YA, tB = ZB - YB, tC = ZC - YC, tD = ZD - YD;
    float tauh = tA[0] + im * tA[1];
    float tauv = tB[0] + im * tB[1];
    f32x2 bU = nqP + ghP * tauh + gvP * tauv;
    f32x2 bP = tC - tB - 100.f;
    f32x2 bS = tA + tD - 50.f;
    float pp = bP[0] + im * bP[1];
    float s2 = bS[0] + im * bS[1];
    f32x2 cb = ghP * s2 - gvP * pp;
    f32x2 ub = bU - cb * rd;
    X01 = iA * ub[0] + iB * ub[1];
    f32x2 gd = gHV0 * X01[0] + gHV1 * X01[1];
    XP = (bP + IM2 * gd[1]) * rd;
    XS = (bS - IM2 * gd[0]) * rd;
    f32x2 ztA = IM2 * gd[0] + XS;
    f32x2 ztB = IM2 * gd[1] - XP;

    f32x2 vv, zn;
    vv = ztA + YA; zn[0] = fmaxf(vv[0], loA[0]); zn[1] = fmaxf(vv[1], loA[1]);
    YA = vv - zn; ZA = zn;
    vv = ztB + YB; zn[0] = fminf(vv[0], hiB[0]); zn[1] = fminf(vv[1], hiB[1]);
    YB = vv - zn; ZB = zn;
    vv = XP + YC;  zn[0] = fmaxf(vv[0], 0.f);   zn[1] = fmaxf(vv[1], 0.f);
    YC = vv - zn; ZC = zn;
    vv = XS + YD;  zn[0] = fmaxf(vv[0], 0.f);   zn[1] = fmaxf(vv[1], 0.f);
    YD = vv - zn; ZD = zn;
  }

  float relax = 0.5f * (XP[0] + XP[1]);
  const float cc = 0.5f * (1.f + im);
  float Vdot = cc * (gv0 * X01[0] + gv1 * X01[1] - gvx);
  float Hdot = cc * (gh0 * X01[0] + gh1 * X01[1] - ghx);

  f32x2 uo; uo[0] = X01[0]; uo[1] = X01[1];
  *(f32x2*)&out[2 * e] = uo;
  out[65536 + e]  = relax;
  out[131072 + e] = Vdot;
  out[196608 + e] = Hdot;
}

extern "C" void kernel_launch(void* const* d_in, const int* in_sizes, int n_in,
                              void* d_out, int out_size, void* d_ws, size_t ws_size,
                              hipStream_t stream) {
  (void)in_sizes; (void)n_in; (void)out_size; (void)d_ws; (void)ws_size;
  fused_kernel<<<512, 256, 0, stream>>>(
      d_in[0], d_in[1], d_in[2], d_in[3], d_in[4], d_in[5], d_in[6],
      d_in[7], d_in[8], d_in[9], d_in[10], d_in[11], d_in[12],
      d_in[13], d_in[14], (float*)d_out);
}

// Round 12
// 101.068 us; speedup vs baseline: 1.6058x; 1.0503x over previous
//
#include <hip/hip_runtime.h>
#include <hip/hip_bf16.h>
#include <math.h>

typedef _Float16 f16x8 __attribute__((ext_vector_type(8)));
typedef _Float16 f16x4 __attribute__((ext_vector_type(4)));
typedef float    f32x4 __attribute__((ext_vector_type(4)));
typedef float    f32x2 __attribute__((ext_vector_type(2)));

__device__ __forceinline__ float ldin(const void* p, int i, int f32f) {
  return f32f ? ((const float*)p)[i]
              : __bfloat162float(((const __hip_bfloat16*)p)[i]);
}

__device__ __forceinline__ f32x4 MFMA(f16x8 a, f16x8 b, f32x4 c) {
  return __builtin_amdgcn_mfma_f32_16x16x32_f16(a, b, c, 0, 0, 0);
}

__device__ __forceinline__ float tanh_fast(float x) {
  float e = __expf(2.f * x);
  return 1.f - 2.f * __builtin_amdgcn_rcpf(e + 1.f);
}

__device__ __forceinline__ float redq(float v) {
  v += __shfl_xor(v, 16, 64);
  v += __shfl_xor(v, 32, 64);
  return v;
}

// ---- LDS panel layout (f16 units), fragment-linear ----
#define OFF_VW2   0
#define OFF_VW2T  4096
#define OFF_HW2   8192
#define OFF_HW2T  12288
#define OFF_HW3   16384
#define OFF_HW3T  20480
#define OFF_W1V   24576
#define OFF_W1H   26624
#define W_N       28672
// f32 constants
#define C_WGV0 0
#define C_WGV1 64
#define C_WGH0 128
#define C_WGH1 192
#define C_VB1  256
#define C_VB2  320
#define C_HB1  384
#define C_HB2  448
#define C_HB3  512
#define C_W4   576
#define C_K    640
#define C_HB4  656
#define C_N    658

// ===========================================================================
// r12 = r11 resubmitted (r11 bench was an infra failure, no data).
// r8 structure (256 blocks x 512 thr, 1 block/CU, wave owns 16 elems x
// all 64 h, V/H interleaved, 2 barriers, full-lane tail on waves 0,2) with
// ONE change: amdgpu_waves_per_eu(2,2). Diagnosis (r9/r10 counters): the
// backend allocated 100-128 VGPRs in every variant (its default 4-wave/SIMD
// occupancy target), but our grid can only ever give 2 waves/SIMD — so the
// scheduler was re-serializing load batches to shrink liveness, defeating
// all ILP restructurings (r3/r4 ~0 gain). Pinning waves/EU to 2 raises the
// register budget to 256 so ds_read batches stay in flight and stages can
// software-pipeline.
// ===========================================================================
__global__ __launch_bounds__(512)
__attribute__((amdgpu_waves_per_eu(2, 2)))
void fused_kernel(
    const void* px, const void* pVW1, const void* pVb1, const void* pVW2, const void* pVb2,
    const void* pHW1, const void* pHb1, const void* pHW2, const void* pHb2,
    const void* pHW3, const void* pHb3, const void* pHW4, const void* pHb4,
    const void* pG0, const void* pK, float* out)
{
  __shared__ __align__(16) _Float16 sW[W_N];          // fragment-linear panels
  __shared__ __align__(16) _Float16 sAct[16][1024];   // [wave][V|H]
  __shared__ __align__(16) float sQPs[10][128];
  __shared__ __align__(16) float sC[C_N];
  __shared__ int sCnt;

  const int tid = threadIdx.x, lane = tid & 63, w = tid >> 6;
  const int n = lane & 15, q = lane >> 4;
  const int e0 = blockIdx.x * 128 + w * 16;

  // ---- (1) dtype detection ----
  if (tid == 0) sCnt = 0;
  __syncthreads();
  {
    const unsigned short* xbp = (const unsigned short*)px;
    int good = 0;
#pragma unroll
    for (int i = 0; i < 2; ++i) {
      int ex = (xbp[tid * 2 + i] >> 7) & 0xFF;
      good += (ex >= 97 && ex <= 157) ? 1 : 0;
    }
    atomicAdd(&sCnt, good);
  }
  __syncthreads();
  const int f32f = (sCnt >= 870) ? 0 : 1;   // >=85% of 1024 sane -> bf16 inputs

  // ---- x row (16B/32B vector load): issue early, consumed after barrier ----
  float xv[8];
  if (f32f) {
    const f32x4* xp = (const f32x4*)((const float*)px + (e0 + n) * 8);
    f32x4 x0 = xp[0], x1 = xp[1];
#pragma unroll
    for (int j = 0; j < 4; ++j) { xv[j] = x0[j]; xv[4 + j] = x1[j]; }
  } else {
    uint4 u = *(const uint4*)((const unsigned short*)px + (e0 + n) * 8);
    unsigned uu[4] = {u.x, u.y, u.z, u.w};
#pragma unroll
    for (int j = 0; j < 4; ++j) {
      xv[2 * j]     = __uint_as_float(uu[j] << 16);
      xv[2 * j + 1] = __uint_as_float(uu[j] & 0xffff0000u);
    }
  }

  // 8 contiguous source elems starting at i0 (i0 % 8 == 0)
  auto ld8 = [&](const void* src, int i0, float* o) {
    if (f32f) {
      f32x4 a = *(const f32x4*)((const float*)src + i0);
      f32x4 b = *(const f32x4*)((const float*)src + i0 + 4);
#pragma unroll
      for (int j = 0; j < 4; ++j) { o[j] = a[j]; o[4 + j] = b[j]; }
    } else {
      uint4 u = *(const uint4*)((const unsigned short*)src + i0);
      unsigned uu[4] = {u.x, u.y, u.z, u.w};
#pragma unroll
      for (int j = 0; j < 4; ++j) {
        o[2 * j]     = __uint_as_float(uu[j] << 16);
        o[2 * j + 1] = __uint_as_float(uu[j] & 0xffff0000u);
      }
    }
  };

  // ---- (2) gather-build panels into LDS: 7 slots/thread, 16B store each ----
  {
    const int s8 = tid & 511;
    const int h  = ((s8 >> 7) << 4) | (s8 & 15);
    const int k0 = (((s8 >> 6) & 1) << 5) | (((s8 >> 4) & 3) << 3);
#pragma unroll
    for (int p = 0; p < 6; ++p) {
      const void* src = (p < 2) ? pVW2 : ((p < 4) ? pHW2 : pHW3);
      f16x8 v;
      if (p & 1) {
        // transposed panel: slot(h,k) holds M[k][h]
#pragma unroll
        for (int j = 0; j < 8; ++j)
          v[j] = (_Float16)ldin(src, (k0 + j) * 64 + h, f32f);
      } else {
        float o[8];
        ld8(src, h * 64 + k0, o);
#pragma unroll
        for (int j = 0; j < 8; ++j) v[j] = (_Float16)o[j];
      }
      *(f16x8*)(sW + p * 4096 + s8 * 8) = v;
    }
    // slots 3072..3583: packed layer-1 A-frags (512 slots = 512 threads)
    {
      const int t2 = tid;
      const void* src = (t2 >> 8) ? pHW1 : pVW1;
      const int off = (t2 >> 8) ? OFF_W1H : OFF_W1V;
      const int ss = t2 & 255;
      const int mm = ss & 15, qq = (ss >> 4) & 3, ht = ss >> 6;
      float o[8];
      ld8(src, (ht * 16 + mm) * 8, o);
      f16x8 v;
#pragma unroll
      for (int j = 0; j < 8; ++j) {
        _Float16 hi = (_Float16)o[j];
        v[j] = (qq < 2) ? hi
             : ((qq == 2 && f32f) ? (_Float16)(o[j] - (float)hi) : (_Float16)0.f);
      }
      *(f16x8*)(sW + off + ss * 8) = v;
    }
  }

  // ---- (3) constants into sC ----
  if (tid < 64) {
    float a0 = 0.f, a1 = 0.f, b0 = 0.f, b1 = 0.f;
#pragma unroll
    for (int nn = 0; nn < 8; ++nn) {
      float g0 = ldin(pG0, 2 * nn, f32f), g1 = ldin(pG0, 2 * nn + 1, f32f);
      float wv = ldin(pVW1, tid * 8 + nn, f32f), wh = ldin(pHW1, tid * 8 + nn, f32f);
      a0 += wv * g0; a1 += wv * g1; b0 += wh * g0; b1 += wh * g1;
    }
    sC[C_WGV0 + tid] = a0; sC[C_WGV1 + tid] = a1;
    sC[C_WGH0 + tid] = b0; sC[C_WGH1 + tid] = b1;
    sC[C_VB1 + tid] = ldin(pVb1, tid, f32f);
    sC[C_VB2 + tid] = ldin(pVb2, tid, f32f);
    sC[C_HB1 + tid] = ldin(pHb1, tid, f32f);
    sC[C_HB2 + tid] = ldin(pHb2, tid, f32f);
    sC[C_HB3 + tid] = ldin(pHb3, tid, f32f);
    sC[C_W4  + tid] = ldin(pHW4, tid, f32f);
  }
  if (tid < 16) sC[C_K + tid] = ldin(pK, tid, f32f);
  if (tid == 0) sC[C_HB4] = ldin(pHb4, 0, f32f);

  __syncthreads();   // sW + sC ready

  float un0 = 0.f, un1 = 0.f;
  f16x8 xb;
#pragma unroll
  for (int j = 0; j < 8; ++j) {
    _Float16 hh = (_Float16)xv[j];
    float lo = xv[j] - (float)hh;
    xb[j] = (q == 1) ? (_Float16)lo : ((q == 3) ? (_Float16)0.f : hh);
    un0 -= xv[j] * sC[C_K + 2 * j];
    un1 -= xv[j] * sC[C_K + 2 * j + 1];
  }

  _Float16* bufV = sAct[2 * w];
  _Float16* bufH = sAct[2 * w + 1];

  // Paired 64x64 stage, all-LDS operands.
  auto gemm64x2 = [&](int poffV, int poffH, f32x4* accV, f32x4* accH) {
    f16x8 aV[8], aH[8];
#pragma unroll
    for (int i = 0; i < 8; ++i)
      aV[i] = *(const f16x8*)(sW + poffV + i * 512 + lane * 8);
#pragma unroll
    for (int i = 0; i < 8; ++i)
      aH[i] = *(const f16x8*)(sW + poffH + i * 512 + lane * 8);
    f16x8 bV0 = *(const f16x8*)(bufV + lane * 8);
    f16x8 bV1 = *(const f16x8*)(bufV + 512 + lane * 8);
    f16x8 bH0 = *(const f16x8*)(bufH + lane * 8);
    f16x8 bH1 = *(const f16x8*)(bufH + 512 + lane * 8);
#pragma unroll
    for (int ht = 0; ht < 4; ++ht) {
      f32x4 c = {0.f, 0.f, 0.f, 0.f};
      c = MFMA(aV[2 * ht], bV0, c);
      accV[ht] = MFMA(aV[2 * ht + 1], bV1, c);
      f32x4 d = {0.f, 0.f, 0.f, 0.f};
      d = MFMA(aH[2 * ht], bH0, d);
      accH[ht] = MFMA(aH[2 * ht + 1], bH1, d);
    }
  };
  auto gemm64 = [&](int poff, const _Float16* b, f32x4* acc) {
    f16x8 a[8];
#pragma unroll
    for (int i = 0; i < 8; ++i)
      a[i] = *(const f16x8*)(sW + poff + i * 512 + lane * 8);
    f16x8 b0 = *(const f16x8*)(b + lane * 8);
    f16x8 b1 = *(const f16x8*)(b + 512 + lane * 8);
#pragma unroll
    for (int ht = 0; ht < 4; ++ht) {
      f32x4 c = {0.f, 0.f, 0.f, 0.f};
      c = MFMA(a[2 * ht], b0, c);
      acc[ht] = MFMA(a[2 * ht + 1], b1, c);
    }
  };
  auto l1gemm2 = [&](f32x4* accV, f32x4* accH) {
    f16x8 aV[4], aH[4];
#pragma unroll
    for (int ht = 0; ht < 4; ++ht)
      aV[ht] = *(const f16x8*)(sW + OFF_W1V + ht * 512 + lane * 8);
#pragma unroll
    for (int ht = 0; ht < 4; ++ht)
      aH[ht] = *(const f16x8*)(sW + OFF_W1H + ht * 512 + lane * 8);
#pragma unroll
    for (int ht = 0; ht < 4; ++ht) {
      f32x4 c = {0.f, 0.f, 0.f, 0.f};
      accV[ht] = MFMA(aV[ht], xb, c);
      f32x4 d = {0.f, 0.f, 0.f, 0.f};
      accH[ht] = MFMA(aH[ht], xb, d);
    }
  };
  auto wst = [&](const f32x4* vals, _Float16* b) {
#pragma unroll
    for (int ht = 0; ht < 4; ++ht) {
      int aw = ((ht >> 1) << 9) + (((ht & 1) * 2 + (q >> 1)) << 7) + n * 8 + ((q & 1) << 2);
      f16x4 vh;
#pragma unroll
      for (int r = 0; r < 4; ++r) vh[r] = (_Float16)vals[ht][r];
      *(f16x4*)(b + aw) = vh;
    }
  };

  f32x4 accV[4], accH[4], tvV[4], tvH[4];
  f32x4 z1V[4], d1V[4], z1H[4], d1H[4], d2H[4];

  // ===== S1: layer-1 both nets =====
  l1gemm2(accV, accH);
#pragma unroll
  for (int ht = 0; ht < 4; ++ht) {
    int hb = ht * 16 + q * 4;
    f32x4 bV = *(const f32x4*)&sC[C_VB1 + hb];
    f32x4 bH = *(const f32x4*)&sC[C_HB1 + hb];
    z1V[ht] = accV[ht]; z1H[ht] = accH[ht];
#pragma unroll
    for (int r = 0; r < 4; ++r) {
      float t = tanh_fast(z1V[ht][r] + bV[r]);
      tvV[ht][r] = t; d1V[ht][r] = 1.f - t * t;
      t = tanh_fast(z1H[ht][r] + bH[r]);
      tvH[ht][r] = t; d1H[ht][r] = 1.f - t * t;
    }
  }
  wst(tvV, bufV); wst(tvH, bufH);

  // ===== S2: layer-2 both nets =====
  gemm64x2(OFF_VW2, OFF_HW2, accV, accH);
  float pV = 0.f;
#pragma unroll
  for (int ht = 0; ht < 4; ++ht) {
    int hb = ht * 16 + q * 4;
    f32x4 bV = *(const f32x4*)&sC[C_VB2 + hb];
    f32x4 bH = *(const f32x4*)&sC[C_HB2 + hb];
#pragma unroll
    for (int r = 0; r < 4; ++r) {
      float t = tanh_fast(accV[ht][r] + bV[r]);
      pV += t * t;
      tvV[ht][r] = t * (1.f - t * t);          // t2 * d2
      t = tanh_fast(accH[ht][r] + bH[r]);
      tvH[ht][r] = t; d2H[ht][r] = 1.f - t * t;
    }
  }
  wst(tvV, bufV); wst(tvH, bufH);

  // ===== S3: V bwd (W2^T) + H layer-3 (W3) =====
  gemm64x2(OFF_VW2T, OFF_HW3, accV, accH);
  float pgvx = 0.f, plv0 = 0.f, plv1 = 0.f, pH = 0.f;
#pragma unroll
  for (int ht = 0; ht < 4; ++ht) {
    int hb = ht * 16 + q * 4;
    f32x4 g0 = *(const f32x4*)&sC[C_WGV0 + hb];
    f32x4 g1 = *(const f32x4*)&sC[C_WGV1 + hb];
    f32x4 bH = *(const f32x4*)&sC[C_HB3 + hb];
    f32x4 w4 = *(const f32x4*)&sC[C_W4 + hb];
#pragma unroll
    for (int r = 0; r < 4; ++r) {
      float wt = accV[ht][r] * d1V[ht][r];
      pgvx += wt * z1V[ht][r];
      plv0 += wt * g0[r]; plv1 += wt * g1[r];
      float t = tanh_fast(accH[ht][r] + bH[r]);
      pH += t * w4[r];
      tvH[ht][r] = w4[r] * (1.f - t * t);      // v4
    }
  }
  wst(tvH, bufH);

  // ===== S4: H bwd (W3^T) =====
  gemm64(OFF_HW3T, bufH, accH);                // v3
#pragma unroll
  for (int ht = 0; ht < 4; ++ht)
#pragma unroll
    for (int r = 0; r < 4; ++r) tvH[ht][r] = accH[ht][r] * d2H[ht][r];   // bb
  wst(tvH, bufH);

  // ===== S5: H bwd (W2^T) =====
  gemm64(OFF_HW2T, bufH, accH);                // v2
  float pghx = 0.f, plh0 = 0.f, plh1 = 0.f;
#pragma unroll
  for (int ht = 0; ht < 4; ++ht) {
    int hb = ht * 16 + q * 4;
    f32x4 g0 = *(const f32x4*)&sC[C_WGH0 + hb];
    f32x4 g1 = *(const f32x4*)&sC[C_WGH1 + hb];
#pragma unroll
    for (int r = 0; r < 4; ++r) {
      float wt = accH[ht][r] * d1H[ht][r];
      pghx += wt * z1H[ht][r];
      plh0 += wt * g0[r]; plh1 += wt * g1[r];
    }
  }

  // ---- per-element scalars: reduce over q, hand off via LDS ----
  {
    float a0 = redq(plh0), a1 = redq(plh1), a2 = redq(plv0), a3 = redq(plv1);
    float a4 = redq(pghx), a5 = redq(pgvx), a6 = redq(pV), a7 = redq(pH);
    if (q == 0) {
      int col = w * 16 + n;
      sQPs[0][col] = a0; sQPs[1][col] = a1; sQPs[2][col] = a2; sQPs[3][col] = a3;
      sQPs[4][col] = a4; sQPs[5][col] = a5; sQPs[6][col] = a6; sQPs[7][col] = a7;
      sQPs[8][col] = un0; sQPs[9][col] = un1;
    }
  }
  __syncthreads();   // scalars ready
  if (w != 0 && w != 2) return;

  // ====== QP tail: waves 0,2 (SIMD0/SIMD2), 64 full lanes = 64 elems ======
  const int col = (w >> 1) * 64 + lane;
  const int e = blockIdx.x * 128 + col;
  float gh0 = sQPs[0][col], gh1 = sQPs[1][col];
  float gv0 = sQPs[2][col], gv1 = sQPs[3][col];
  float ghx = sQPs[4][col], gvx = sQPs[5][col];
  float V   = 0.5f * sQPs[6][col];
  float H   = sQPs[7][col] + sC[C_HB4];
  un0 = sQPs[8][col]; un1 = sQPs[9][col];
  out[98304 + e]  = V;
  out[163840 + e] = H;

  const float im = 1.0f / 1.2f;
  const float sg = 1e-6f;
  const float d  = 2.f + sg;
  const float rd = 1.f / d;
  const float al = 1.f + im * im;
  const float be = al * (1.f - rd);
  float S00 = be * (gh0 * gh0 + gv0 * gv0) + d;
  float S11 = be * (gh1 * gh1 + gv1 * gv1) + d;
  float S01 = be * (gh0 * gh1 + gv0 * gv1);
  float idet = 1.f / (S00 * S11 - S01 * S01);

  // packed coefficient pairs
  f32x2 IM2; IM2[0] = 1.f; IM2[1] = im;
  f32x2 ghP; ghP[0] = gh0; ghP[1] = gh1;
  f32x2 gvP; gvP[0] = gv0; gvP[1] = gv1;
  f32x2 gHV0; gHV0[0] = gh0; gHV0[1] = gv0;
  f32x2 gHV1; gHV1[0] = gh1; gHV1[1] = gv1;
  f32x2 iA; iA[0] = S11 * idet;  iA[1] = -S01 * idet;
  f32x2 iB; iB[0] = -S01 * idet; iB[1] = S00 * idet;
  f32x2 nqP; nqP[0] = 2.f * un0; nqP[1] = 2.f * un1;
  f32x2 loA; loA[0] = ghx - H;      loA[1] = ghx * im - H;
  f32x2 hiB; hiB[0] = gvx - V;      hiB[1] = gvx * im - V;

  // state pairs: A=(Z0,Z2) B=(Z1,Z3) C=(Z4,Z5) D=(Z6,Z7)
  f32x2 ZA = {0.f, 0.f}, ZB = {0.f, 0.f}, ZC = {0.f, 0.f}, ZD = {0.f, 0.f};
  f32x2 YA = {0.f, 0.f}, YB = {0.f, 0.f}, YC = {0.f, 0.f}, YD = {0.f, 0.f};
  f32x2 X01 = {0.f, 0.f}, XP = {0.f, 0.f}, XS = {0.f, 0.f};

  // sg*X proximal terms dropped from rhs: shifts the fixed point by O(1e-6).
#pragma unroll 1
  for (int it = 0; it < 80; ++it) {
    f32x2 tA = ZA - YA, tB = ZB - YB, tC = ZC - YC, tD = ZD - YD;
    float tauh = tA[0] + im * tA[1];
    float tauv = tB[0] + im * tB[1];
    f32x2 bU = nqP + ghP * tauh + gvP * tauv;
    f32x2 bP = tC - tB - 100.f;
    f32x2 bS = tA + tD - 50.f;
    float pp = bP[0] + im * bP[1];
    float s2 = bS[0] + im * bS[1];
    f32x2 cb = ghP * s2 - gvP * pp;
    f32x2 ub = bU - cb * rd;
    X01 = iA * ub[0] + iB * ub[1];
    f32x2 gd = gHV0 * X01[0] + gHV1 * X01[1];
    XP = (bP + IM2 * gd[1]) * rd;
    XS = (bS - IM2 * gd[0]) * rd;
    f32x2 ztA = IM2 * gd[0] + XS;
    f32x2 ztB = IM2 * gd[1] - XP;

    f32x2 vv, zn;
    vv = ztA + YA; zn[0] = fmaxf(vv[0], loA[0]); zn[1] = fmaxf(vv[1], loA[1]);
    YA = vv - zn; ZA = zn;
    vv = ztB + YB; zn[0] = fminf(vv[0], hiB[0]); zn[1] = fminf(vv[1], hiB[1]);
    YB = vv - zn; ZB = zn;
    vv = XP + YC;  zn[0] = fmaxf(vv[0], 0.f);   zn[1] = fmaxf(vv[1], 0.f);
    YC = vv - zn; ZC = zn;
    vv = XS + YD;  zn[0] = fmaxf(vv[0], 0.f);   zn[1] = fmaxf(vv[1], 0.f);
    YD = vv - zn; ZD = zn;
  }

  float relax = 0.5f * (XP[0] + XP[1]);
  const float cc = 0.5f * (1.f + im);
  float Vdot = cc * (gv0 * X01[0] + gv1 * X01[1] - gvx);
  float Hdot = cc * (gh0 * X01[0] + gh1 * X01[1] - ghx);

  f32x2 uo; uo[0] = X01[0]; uo[1] = X01[1];
  *(f32x2*)&out[2 * e] = uo;
  out[65536 + e]  = relax;
  out[131072 + e] = Vdot;
  out[196608 + e] = Hdot;
}

extern "C" void kernel_launch(void* const* d_in, const int* in_sizes, int n_in,
                              void* d_out, int out_size, void* d_ws, size_t ws_size,
                              hipStream_t stream) {
  (void)in_sizes; (void)n_in; (void)out_size; (void)d_ws; (void)ws_size;
  fused_kernel<<<256, 512, 0, stream>>>(
      d_in[0], d_in[1], d_in[2], d_in[3], d_in[4], d_in[5], d_in[6],
      d_in[7], d_in[8], d_in[9], d_in[10], d_in[11], d_in[12],
      d_in[13], d_in[14], (float*)d_out);
}